// Round 6
// baseline (1504.893 us; speedup 1.0000x reference)
//
#include <hip/hip_runtime.h>
#include <math.h>

#define NTOT 32768
#define DMODEL 768
#define BSZ 128
#define NHEAD 16
#define DH 48
#define BETA 0.25f

typedef _Float16 f16;
typedef f16 f16x8 __attribute__((ext_vector_type(8)));
typedef f16 f16x4 __attribute__((ext_vector_type(4)));
typedef float f32x4 __attribute__((ext_vector_type(4)));

// ---------------------------------------------------------------------------
// Row stats: mean, rstd (LN, biased var, eps=1e-5), optional l2inv of raw row.
// ---------------------------------------------------------------------------
__global__ __launch_bounds__(256)
void row_stats(const float* __restrict__ X, int M, float* __restrict__ mean,
               float* __restrict__ rstd, float* __restrict__ l2inv) {
  const int row = blockIdx.x * 4 + (threadIdx.x >> 6);
  const int lane = threadIdx.x & 63;
  if (row >= M) return;
  const float* x = X + (size_t)row * DMODEL;
  float s = 0.f, s2 = 0.f;
  for (int i = lane; i < DMODEL; i += 64) {
    float v = x[i];
    s += v; s2 += v * v;
  }
#pragma unroll
  for (int off = 32; off; off >>= 1) {
    s  += __shfl_xor(s, off);
    s2 += __shfl_xor(s2, off);
  }
  if (lane == 0) {
    float mu = s * (1.f / DMODEL);
    float var = s2 * (1.f / DMODEL) - mu * mu;
    mean[row] = mu;
    rstd[row] = rsqrtf(var + 1e-5f);
    if (l2inv) l2inv[row] = 1.f / fmaxf(sqrtf(s2), 1e-12f);
  }
}

// ---------------------------------------------------------------------------
// split_ln: nh = (x - mu)*rstd per row, split fp16 hi/lo. 8 elems/thread.
// ---------------------------------------------------------------------------
__global__ __launch_bounds__(256)
void split_ln(const float* __restrict__ X, const float* __restrict__ mean,
              const float* __restrict__ rstd, f16* __restrict__ hi,
              f16* __restrict__ lo) {
  const int i8 = blockIdx.x * 256 + threadIdx.x;
  const int row = i8 / 96;  // 768/8 elems per row
  const float mu = mean[row], rs = rstd[row];
  const float* xp = X + (size_t)i8 * 8;
  const float4 a = *(const float4*)xp;
  const float4 b = *(const float4*)(xp + 4);
  const float x[8] = {a.x, a.y, a.z, a.w, b.x, b.y, b.z, b.w};
  f16x8 h, l;
#pragma unroll
  for (int j = 0; j < 8; j++) {
    const float s = (x[j] - mu) * rs;
    const f16 hv = (f16)s;
    h[j] = hv;
    l[j] = (f16)(s - (float)hv);
  }
  *(f16x8*)(hi + (size_t)i8 * 8) = h;
  *(f16x8*)(lo + (size_t)i8 * 8) = l;
}

// ---------------------------------------------------------------------------
// split_plain: raw fp32 -> fp16 hi/lo. 8 elems/thread.
// ---------------------------------------------------------------------------
__global__ __launch_bounds__(256)
void split_plain(const float* __restrict__ X, f16* __restrict__ hi,
                 f16* __restrict__ lo) {
  const int i8 = blockIdx.x * 256 + threadIdx.x;
  const float* xp = X + (size_t)i8 * 8;
  const float4 a = *(const float4*)xp;
  const float4 b = *(const float4*)(xp + 4);
  const float x[8] = {a.x, a.y, a.z, a.w, b.x, b.y, b.z, b.w};
  f16x8 h, l;
#pragma unroll
  for (int j = 0; j < 8; j++) {
    const f16 hv = (f16)x[j];
    h[j] = hv;
    l[j] = (f16)(x[j] - (float)hv);
  }
  *(f16x8*)(hi + (size_t)i8 * 8) = h;
  *(f16x8*)(lo + (size_t)i8 * 8) = l;
}

// ---------------------------------------------------------------------------
// prep_w: combined W' (o<768: g_k*Wk rows; o>=768: g_v*Wv rows), scaled x16,
// split fp16 hi/lo; biasc[o] = bias[o] + sum_d bln[d]*W[o,d].
// ---------------------------------------------------------------------------
__global__ __launch_bounds__(256)
void prep_w(const float* __restrict__ Wk, const float* __restrict__ bk,
            const float* __restrict__ gk, const float* __restrict__ blnk,
            const float* __restrict__ Wv, const float* __restrict__ bv,
            const float* __restrict__ gv, const float* __restrict__ blnv,
            f16* __restrict__ Wc_hi, f16* __restrict__ Wc_lo,
            float* __restrict__ biasc) {
  const int o = blockIdx.x * 4 + (threadIdx.x >> 6);  // 0..1535
  const int lane = threadIdx.x & 63;
  const bool isK = o < DMODEL;
  const float* W = isK ? (Wk + (size_t)o * DMODEL)
                       : (Wv + (size_t)(o - DMODEL) * DMODEL);
  const float* g   = isK ? gk : gv;
  const float* bln = isK ? blnk : blnv;
  float bacc = 0.f;
  for (int d = lane * 4; d < DMODEL; d += 256) {
    const float4 wv = *(const float4*)(W + d);
    const float4 g4 = *(const float4*)(g + d);
    const float4 b4 = *(const float4*)(bln + d);
    bacc += wv.x * b4.x + wv.y * b4.y + wv.z * b4.z + wv.w * b4.w;
    const float sv[4] = {wv.x * g4.x * 16.f, wv.y * g4.y * 16.f,
                         wv.z * g4.z * 16.f, wv.w * g4.w * 16.f};
    f16x4 h4, l4;
#pragma unroll
    for (int j = 0; j < 4; j++) {
      const f16 h = (f16)sv[j];
      h4[j] = h;
      l4[j] = (f16)(sv[j] - (float)h);
    }
    *(f16x4*)(Wc_hi + (size_t)o * DMODEL + d) = h4;
    *(f16x4*)(Wc_lo + (size_t)o * DMODEL + d) = l4;
  }
#pragma unroll
  for (int off = 32; off; off >>= 1) bacc += __shfl_xor(bacc, off);
  if (lane == 0) biasc[o] = (isK ? bk[o] : bv[o - DMODEL]) + bacc;
}

// ---------------------------------------------------------------------------
// Fused dual projection GEMM (pre-split A): C = nh . Wc'/16 + biasc.
// Tiles 128x128, BK=32, 4 waves 2x2, 3-term split MFMA. Both A and B staged
// as pure fp16 copies. Layouts per HW-verified 16x16x32.
// ---------------------------------------------------------------------------
__global__ __launch_bounds__(256)
void proj_dual_v2(const f16* __restrict__ nh_hi, const f16* __restrict__ nh_lo,
                  const f16* __restrict__ Wc_hi, const f16* __restrict__ Wc_lo,
                  const float* __restrict__ biasc,
                  f16* __restrict__ k_hi, f16* __restrict__ k_lo,
                  f16* __restrict__ v_hi, f16* __restrict__ v_lo) {
  __shared__ __align__(16) f16 As[2][128][40];
  __shared__ __align__(16) f16 Bs[2][128][40];
  const int t = threadIdx.x;
  const int n0 = blockIdx.x * 128;
  const int m0 = blockIdx.y * 128;
  const int w = t >> 6, lane = t & 63;
  const int l15 = lane & 15, lq = lane >> 4;
  const int wm = w >> 1, wn = w & 1;
  const int sr = t >> 1, sh = t & 1;

  f32x4 acc[4][4];
#pragma unroll
  for (int a = 0; a < 4; a++)
#pragma unroll
    for (int b = 0; b < 4; b++)
#pragma unroll
      for (int r = 0; r < 4; r++) acc[a][b][r] = 0.f;

  for (int k0 = 0; k0 < DMODEL; k0 += 32) {
    __syncthreads();
    {
      const size_t aoff = (size_t)(m0 + sr) * DMODEL + k0 + sh * 16;
      f16x8 ah0 = *(const f16x8*)(nh_hi + aoff);
      f16x8 ah1 = *(const f16x8*)(nh_hi + aoff + 8);
      f16x8 al0 = *(const f16x8*)(nh_lo + aoff);
      f16x8 al1 = *(const f16x8*)(nh_lo + aoff + 8);
      *(f16x8*)&As[0][sr][sh * 16] = ah0;
      *(f16x8*)&As[0][sr][sh * 16 + 8] = ah1;
      *(f16x8*)&As[1][sr][sh * 16] = al0;
      *(f16x8*)&As[1][sr][sh * 16 + 8] = al1;
    }
    {
      const size_t boff = (size_t)(n0 + sr) * DMODEL + k0 + sh * 16;
      f16x8 bh0 = *(const f16x8*)(Wc_hi + boff);
      f16x8 bh1 = *(const f16x8*)(Wc_hi + boff + 8);
      f16x8 bl0 = *(const f16x8*)(Wc_lo + boff);
      f16x8 bl1 = *(const f16x8*)(Wc_lo + boff + 8);
      *(f16x8*)&Bs[0][sr][sh * 16] = bh0;
      *(f16x8*)&Bs[0][sr][sh * 16 + 8] = bh1;
      *(f16x8*)&Bs[1][sr][sh * 16] = bl0;
      *(f16x8*)&Bs[1][sr][sh * 16 + 8] = bl1;
    }
    __syncthreads();
    f16x8 nhh[4], nhl[4];
#pragma unroll
    for (int fm = 0; fm < 4; fm++) {
      const int row = wm * 64 + fm * 16 + l15;
      nhh[fm] = *(const f16x8*)&As[0][row][lq * 8];
      nhl[fm] = *(const f16x8*)&As[1][row][lq * 8];
    }
    f16x8 wh[4], wl[4];
#pragma unroll
    for (int fo = 0; fo < 4; fo++) {
      const int row = wn * 64 + fo * 16 + l15;
      wh[fo] = *(const f16x8*)&Bs[0][row][lq * 8];
      wl[fo] = *(const f16x8*)&Bs[1][row][lq * 8];
    }
#pragma unroll
    for (int fo = 0; fo < 4; fo++)
#pragma unroll
      for (int fm = 0; fm < 4; fm++) {
        f32x4 a = acc[fo][fm];
        a = __builtin_amdgcn_mfma_f32_16x16x32_f16(wh[fo], nhh[fm], a, 0, 0, 0);
        a = __builtin_amdgcn_mfma_f32_16x16x32_f16(wh[fo], nhl[fm], a, 0, 0, 0);
        a = __builtin_amdgcn_mfma_f32_16x16x32_f16(wl[fo], nhh[fm], a, 0, 0, 0);
        acc[fo][fm] = a;
      }
  }
  const int oc = n0 + wn * 64;
  const bool isK = oc < DMODEL;
  f16* oh = isK ? k_hi : v_hi;
  f16* ol = isK ? k_lo : v_lo;
  const int obase = (isK ? oc : oc - DMODEL) + lq * 4;
#pragma unroll
  for (int fo = 0; fo < 4; fo++) {
    const float4 bb = *(const float4*)(biasc + oc + fo * 16 + lq * 4);
    const float bbv[4] = {bb.x, bb.y, bb.z, bb.w};
    const int o = obase + fo * 16;
#pragma unroll
    for (int fm = 0; fm < 4; fm++) {
      const size_t moff = (size_t)(m0 + wm * 64 + fm * 16 + l15) * DMODEL + o;
      f16x4 h4, l4;
#pragma unroll
      for (int r = 0; r < 4; r++) {
        const float v = acc[fo][fm][r] * 0.0625f + bbv[r];
        const f16 h = (f16)v;
        h4[r] = h;
        l4[r] = (f16)(v - (float)h);
      }
      *(f16x4*)(oh + moff) = h4;
      *(f16x4*)(ol + moff) = l4;
    }
  }
}

// ---------------------------------------------------------------------------
// Fallback proj (round-5 version, in-kernel A split) for small workspaces.
// ---------------------------------------------------------------------------
__global__ __launch_bounds__(256)
void proj_dual_insplit(const float* __restrict__ mb, const float* __restrict__ mean,
                       const float* __restrict__ rstd,
                       const f16* __restrict__ Wc_hi, const f16* __restrict__ Wc_lo,
                       const float* __restrict__ biasc,
                       f16* __restrict__ k_hi, f16* __restrict__ k_lo,
                       f16* __restrict__ v_hi, f16* __restrict__ v_lo) {
  __shared__ __align__(16) f16 As[2][128][40];
  __shared__ __align__(16) f16 Bs[2][128][40];
  const int t = threadIdx.x;
  const int n0 = blockIdx.x * 128;
  const int m0 = blockIdx.y * 128;
  const int w = t >> 6, lane = t & 63;
  const int l15 = lane & 15, lq = lane >> 4;
  const int wm = w >> 1, wn = w & 1;
  const int sr = t >> 1, sh = t & 1;
  const float mu = mean[m0 + sr];
  const float rs = rstd[m0 + sr];
  f32x4 acc[4][4];
#pragma unroll
  for (int a = 0; a < 4; a++)
#pragma unroll
    for (int b = 0; b < 4; b++)
#pragma unroll
      for (int r = 0; r < 4; r++) acc[a][b][r] = 0.f;
  for (int k0 = 0; k0 < DMODEL; k0 += 32) {
    __syncthreads();
    {
      const float* ap = mb + (size_t)(m0 + sr) * DMODEL + k0 + sh * 16;
      float x[16];
#pragma unroll
      for (int c = 0; c < 4; c++) {
        const float4 v4 = *(const float4*)(ap + c * 4);
        x[c * 4 + 0] = v4.x; x[c * 4 + 1] = v4.y;
        x[c * 4 + 2] = v4.z; x[c * 4 + 3] = v4.w;
      }
      f16x8 h0, h1, l0, l1;
#pragma unroll
      for (int j = 0; j < 8; j++) {
        const float s = (x[j] - mu) * rs;
        const f16 h = (f16)s;
        h0[j] = h; l0[j] = (f16)(s - (float)h);
      }
#pragma unroll
      for (int j = 0; j < 8; j++) {
        const float s = (x[8 + j] - mu) * rs;
        const f16 h = (f16)s;
        h1[j] = h; l1[j] = (f16)(s - (float)h);
      }
      *(f16x8*)&As[0][sr][sh * 16] = h0;
      *(f16x8*)&As[0][sr][sh * 16 + 8] = h1;
      *(f16x8*)&As[1][sr][sh * 16] = l0;
      *(f16x8*)&As[1][sr][sh * 16 + 8] = l1;
    }
    {
      const size_t boff = (size_t)(n0 + sr) * DMODEL + k0 + sh * 16;
      f16x8 bh0 = *(const f16x8*)(Wc_hi + boff);
      f16x8 bh1 = *(const f16x8*)(Wc_hi + boff + 8);
      f16x8 bl0 = *(const f16x8*)(Wc_lo + boff);
      f16x8 bl1 = *(const f16x8*)(Wc_lo + boff + 8);
      *(f16x8*)&Bs[0][sr][sh * 16] = bh0;
      *(f16x8*)&Bs[0][sr][sh * 16 + 8] = bh1;
      *(f16x8*)&Bs[1][sr][sh * 16] = bl0;
      *(f16x8*)&Bs[1][sr][sh * 16 + 8] = bl1;
    }
    __syncthreads();
    f16x8 nhh[4], nhl[4];
#pragma unroll
    for (int fm = 0; fm < 4; fm++) {
      const int row = wm * 64 + fm * 16 + l15;
      nhh[fm] = *(const f16x8*)&As[0][row][lq * 8];
      nhl[fm] = *(const f16x8*)&As[1][row][lq * 8];
    }
    f16x8 wh[4], wl[4];
#pragma unroll
    for (int fo = 0; fo < 4; fo++) {
      const int row = wn * 64 + fo * 16 + l15;
      wh[fo] = *(const f16x8*)&Bs[0][row][lq * 8];
      wl[fo] = *(const f16x8*)&Bs[1][row][lq * 8];
    }
#pragma unroll
    for (int fo = 0; fo < 4; fo++)
#pragma unroll
      for (int fm = 0; fm < 4; fm++) {
        f32x4 a = acc[fo][fm];
        a = __builtin_amdgcn_mfma_f32_16x16x32_f16(wh[fo], nhh[fm], a, 0, 0, 0);
        a = __builtin_amdgcn_mfma_f32_16x16x32_f16(wh[fo], nhl[fm], a, 0, 0, 0);
        a = __builtin_amdgcn_mfma_f32_16x16x32_f16(wl[fo], nhh[fm], a, 0, 0, 0);
        acc[fo][fm] = a;
      }
  }
  const int oc = n0 + wn * 64;
  const bool isK = oc < DMODEL;
  f16* oh = isK ? k_hi : v_hi;
  f16* ol = isK ? k_lo : v_lo;
  const int obase = (isK ? oc : oc - DMODEL) + lq * 4;
#pragma unroll
  for (int fo = 0; fo < 4; fo++) {
    const float4 bb = *(const float4*)(biasc + oc + fo * 16 + lq * 4);
    const float bbv[4] = {bb.x, bb.y, bb.z, bb.w};
    const int o = obase + fo * 16;
#pragma unroll
    for (int fm = 0; fm < 4; fm++) {
      const size_t moff = (size_t)(m0 + wm * 64 + fm * 16 + l15) * DMODEL + o;
      f16x4 h4, l4;
#pragma unroll
      for (int r = 0; r < 4; r++) {
        const float v = acc[fo][fm][r] * 0.0625f + bbv[r];
        const f16 h = (f16)v;
        h4[r] = h;
        l4[r] = (f16)(v - (float)h);
      }
      *(f16x4*)(oh + moff) = h4;
      *(f16x4*)(ol + moff) = l4;
    }
  }
}

// ---------------------------------------------------------------------------
// logits via MFMA 3-term split: out[b][n] = 20*ainv[b]*binv[n]*(rq[b].mb[n]).
// Grid: 256 n-blocks of 128 n x 128 b. A = mb rows (free=n), B = rq (free=b).
// ---------------------------------------------------------------------------
__global__ __launch_bounds__(256)
void logits_mfma(const f16* __restrict__ mb_hi, const f16* __restrict__ mb_lo,
                 const f16* __restrict__ rq_hi, const f16* __restrict__ rq_lo,
                 const float* __restrict__ ainv, const float* __restrict__ binv,
                 float* __restrict__ out) {
  __shared__ __align__(16) f16 As[2][128][40];
  __shared__ __align__(16) f16 Bs[2][128][40];
  const int t = threadIdx.x;
  const int n0 = blockIdx.x * 128;
  const int w = t >> 6, lane = t & 63;
  const int l15 = lane & 15, lq = lane >> 4;
  const int wb = w >> 1, wn = w & 1;
  const int sr = t >> 1, sh = t & 1;

  f32x4 acc[4][4];  // [fn][fb]
#pragma unroll
  for (int a = 0; a < 4; a++)
#pragma unroll
    for (int b = 0; b < 4; b++)
#pragma unroll
      for (int r = 0; r < 4; r++) acc[a][b][r] = 0.f;

  for (int k0 = 0; k0 < DMODEL; k0 += 32) {
    __syncthreads();
    {
      const size_t aoff = (size_t)(n0 + sr) * DMODEL + k0 + sh * 16;
      f16x8 ah0 = *(const f16x8*)(mb_hi + aoff);
      f16x8 ah1 = *(const f16x8*)(mb_hi + aoff + 8);
      f16x8 al0 = *(const f16x8*)(mb_lo + aoff);
      f16x8 al1 = *(const f16x8*)(mb_lo + aoff + 8);
      *(f16x8*)&As[0][sr][sh * 16] = ah0;
      *(f16x8*)&As[0][sr][sh * 16 + 8] = ah1;
      *(f16x8*)&As[1][sr][sh * 16] = al0;
      *(f16x8*)&As[1][sr][sh * 16 + 8] = al1;
    }
    {
      const size_t boff = (size_t)sr * DMODEL + k0 + sh * 16;
      f16x8 bh0 = *(const f16x8*)(rq_hi + boff);
      f16x8 bh1 = *(const f16x8*)(rq_hi + boff + 8);
      f16x8 bl0 = *(const f16x8*)(rq_lo + boff);
      f16x8 bl1 = *(const f16x8*)(rq_lo + boff + 8);
      *(f16x8*)&Bs[0][sr][sh * 16] = bh0;
      *(f16x8*)&Bs[0][sr][sh * 16 + 8] = bh1;
      *(f16x8*)&Bs[1][sr][sh * 16] = bl0;
      *(f16x8*)&Bs[1][sr][sh * 16 + 8] = bl1;
    }
    __syncthreads();
    f16x8 ah[4], al[4];  // A (mb), free = n
#pragma unroll
    for (int fn = 0; fn < 4; fn++) {
      const int row = wn * 64 + fn * 16 + l15;
      ah[fn] = *(const f16x8*)&As[0][row][lq * 8];
      al[fn] = *(const f16x8*)&As[1][row][lq * 8];
    }
    f16x8 bh[4], bl[4];  // B (rq), free = b
#pragma unroll
    for (int fb = 0; fb < 4; fb++) {
      const int row = wb * 64 + fb * 16 + l15;
      bh[fb] = *(const f16x8*)&Bs[0][row][lq * 8];
      bl[fb] = *(const f16x8*)&Bs[1][row][lq * 8];
    }
#pragma unroll
    for (int fn = 0; fn < 4; fn++)
#pragma unroll
      for (int fb = 0; fb < 4; fb++) {
        f32x4 a = acc[fn][fb];
        a = __builtin_amdgcn_mfma_f32_16x16x32_f16(ah[fn], bh[fb], a, 0, 0, 0);
        a = __builtin_amdgcn_mfma_f32_16x16x32_f16(ah[fn], bl[fb], a, 0, 0, 0);
        a = __builtin_amdgcn_mfma_f32_16x16x32_f16(al[fn], bh[fb], a, 0, 0, 0);
        acc[fn][fb] = a;
      }
  }
  // Epilogue: col = b (lane&15 within fb tile), row = n (lq*4+r within fn).
#pragma unroll
  for (int fn = 0; fn < 4; fn++) {
    const int gn = n0 + wn * 64 + fn * 16 + lq * 4;
    const float4 bi4 = *(const float4*)(binv + gn);
    const float bi[4] = {bi4.x, bi4.y, bi4.z, bi4.w};
#pragma unroll
    for (int fb = 0; fb < 4; fb++) {
      const int b = wb * 64 + fb * 16 + l15;
      const float sa = 20.f * ainv[b];
      f32x4 o;
#pragma unroll
      for (int r = 0; r < 4; r++) o[r] = acc[fn][fb][r] * sa * bi[r];
      *(f32x4*)(out + (size_t)b * NTOT + gn) = o;
    }
  }
}

// ---------------------------------------------------------------------------
// LN-fused GEMM, fp32 output (for q projection).
// ---------------------------------------------------------------------------
__global__ __launch_bounds__(256)
void ln_gemm_f32(const float* __restrict__ A, const float* __restrict__ mean,
                 const float* __restrict__ rstd, const float* __restrict__ g,
                 const float* __restrict__ bln, const float* __restrict__ W,
                 const float* __restrict__ bias, float* __restrict__ out) {
  __shared__ float As[16][68];
  __shared__ float Ws[16][68];
  const int t = threadIdx.x;
  const int m0 = blockIdx.y << 6, n0 = blockIdx.x << 6;
  const int tm = t >> 4, tn = t & 15;
  const int lr = t >> 2;
  const int lk = (t & 3) << 2;
  const float muL = mean[m0 + lr];
  const float rsL = rstd[m0 + lr];
  float acc[4][4] = {};
  for (int k0 = 0; k0 < DMODEL; k0 += 16) {
    float4 a4 = *(const float4*)(A + (size_t)(m0 + lr) * DMODEL + k0 + lk);
    float4 g4 = *(const float4*)(g + k0 + lk);
    float4 b4 = *(const float4*)(bln + k0 + lk);
    As[lk + 0][lr] = (a4.x - muL) * rsL * g4.x + b4.x;
    As[lk + 1][lr] = (a4.y - muL) * rsL * g4.y + b4.y;
    As[lk + 2][lr] = (a4.z - muL) * rsL * g4.z + b4.z;
    As[lk + 3][lr] = (a4.w - muL) * rsL * g4.w + b4.w;
    float4 w4 = *(const float4*)(W + (size_t)(n0 + lr) * DMODEL + k0 + lk);
    Ws[lk + 0][lr] = w4.x;
    Ws[lk + 1][lr] = w4.y;
    Ws[lk + 2][lr] = w4.z;
    Ws[lk + 3][lr] = w4.w;
    __syncthreads();
#pragma unroll
    for (int kk = 0; kk < 16; kk++) {
      const float4 av = *(const float4*)(&As[kk][tm * 4]);
      const float4 bv = *(const float4*)(&Ws[kk][tn * 4]);
      const float a[4] = {av.x, av.y, av.z, av.w};
      const float b[4] = {bv.x, bv.y, bv.z, bv.w};
#pragma unroll
      for (int i = 0; i < 4; i++)
#pragma unroll
        for (int j = 0; j < 4; j++) acc[i][j] += a[i] * b[j];
    }
    __syncthreads();
  }
  const float4 bia = *(const float4*)(bias + n0 + tn * 4);
  const float bb[4] = {bia.x, bia.y, bia.z, bia.w};
#pragma unroll
  for (int i = 0; i < 4; i++) {
    const int m = m0 + tm * 4 + i;
    float4 o4;
    o4.x = acc[i][0] + bb[0];
    o4.y = acc[i][1] + bb[1];
    o4.z = acc[i][2] + bb[2];
    o4.w = acc[i][3] + bb[3];
    *(float4*)(out + (size_t)m * DMODEL + n0 + tn * 4) = o4;
  }
}

// ---------------------------------------------------------------------------
// Plain small GEMM: out = act(A @ W^T + bias [+ add])
// ---------------------------------------------------------------------------
__global__ __launch_bounds__(256)
void gemm_bias(const float* __restrict__ A, const float* __restrict__ W,
               const float* __restrict__ bias, const float* __restrict__ add,
               float* __restrict__ out, int relu) {
  __shared__ float As[16][68];
  __shared__ float Ws[16][68];
  const int t = threadIdx.x;
  const int m0 = blockIdx.y << 6, n0 = blockIdx.x << 6;
  const int tm = t >> 4, tn = t & 15;
  const int lr = t >> 2;
  const int lk = (t & 3) << 2;
  float acc[4][4] = {};
  for (int k0 = 0; k0 < DMODEL; k0 += 16) {
    float4 a4 = *(const float4*)(A + (size_t)(m0 + lr) * DMODEL + k0 + lk);
    As[lk + 0][lr] = a4.x;
    As[lk + 1][lr] = a4.y;
    As[lk + 2][lr] = a4.z;
    As[lk + 3][lr] = a4.w;
    float4 w4 = *(const float4*)(W + (size_t)(n0 + lr) * DMODEL + k0 + lk);
    Ws[lk + 0][lr] = w4.x;
    Ws[lk + 1][lr] = w4.y;
    Ws[lk + 2][lr] = w4.z;
    Ws[lk + 3][lr] = w4.w;
    __syncthreads();
#pragma unroll
    for (int kk = 0; kk < 16; kk++) {
      const float4 av = *(const float4*)(&As[kk][tm * 4]);
      const float4 bv = *(const float4*)(&Ws[kk][tn * 4]);
      const float a[4] = {av.x, av.y, av.z, av.w};
      const float b[4] = {bv.x, bv.y, bv.z, bv.w};
#pragma unroll
      for (int i = 0; i < 4; i++)
#pragma unroll
        for (int j = 0; j < 4; j++) acc[i][j] += a[i] * b[j];
    }
    __syncthreads();
  }
  const float4 bia = *(const float4*)(bias + n0 + tn * 4);
  const float bb[4] = {bia.x, bia.y, bia.z, bia.w};
#pragma unroll
  for (int i = 0; i < 4; i++) {
    const int m = m0 + tm * 4 + i;
    float v[4];
#pragma unroll
    for (int j = 0; j < 4; j++) v[j] = acc[i][j] + bb[j];
    if (add) {
      const float4 a4 = *(const float4*)(add + (size_t)m * DMODEL + n0 + tn * 4);
      v[0] += a4.x; v[1] += a4.y; v[2] += a4.z; v[3] += a4.w;
    }
    if (relu) {
#pragma unroll
      for (int j = 0; j < 4; j++) v[j] = fmaxf(v[j], 0.f);
    }
    float4 o4 = {v[0], v[1], v[2], v[3]};
    *(float4*)(out + (size_t)m * DMODEL + n0 + tn * 4) = o4;
  }
}

// ---------------------------------------------------------------------------
// Split xi (fp32) into beta-scaled fp16 hi/lo pair.
// ---------------------------------------------------------------------------
__global__ __launch_bounds__(256)
void split_xi_k(const float* __restrict__ xi, f16* __restrict__ hi,
                f16* __restrict__ lo) {
  const int i = blockIdx.x * 256 + threadIdx.x;
  float4 v = ((const float4*)xi)[i];
  float s[4] = {v.x * BETA, v.y * BETA, v.z * BETA, v.w * BETA};
  f16x4 h4, l4;
#pragma unroll
  for (int j = 0; j < 4; j++) {
    f16 h = (f16)s[j];
    h4[j] = h;
    l4[j] = (f16)(s[j] - (float)h);
  }
  ((f16x4*)hi)[i] = h4;
  ((f16x4*)lo)[i] = l4;
}

// ---------------------------------------------------------------------------
// MFMA flash attention round, full hi/lo precision (unchanged structure;
// valIsK skips the redundant value load when value == k).
// ---------------------------------------------------------------------------
#define FCHUNK 64
#define FROWS (NTOT / FCHUNK)  // 512

__global__ __launch_bounds__(256)
void flash_round(const f16* __restrict__ k_hi, const f16* __restrict__ k_lo,
                 const f16* __restrict__ val_hi, const f16* __restrict__ val_lo,
                 const f16* __restrict__ xi_hi, const f16* __restrict__ xi_lo,
                 float* __restrict__ part_ml, float* __restrict__ part_o,
                 int valIsK) {
  const int h = blockIdx.y, chunk = blockIdx.x;
  const int tid = threadIdx.x, w = tid >> 6, lane = tid & 63;
  const int l15 = lane & 15, lq = lane >> 4;
  const int b0 = w * 32;

  __shared__ __align__(16) f16 krow[2][32][56];
  __shared__ __align__(16) f16 vT[2][48][40];
  __shared__ __align__(16) f16 pHi[4][32][40];
  __shared__ __align__(16) f16 pLo[4][32][40];

  const f16x8 zf = {};
  f16x8 xqh[2][2], xql[2][2];
#pragma unroll
  for (int bt = 0; bt < 2; bt++) {
    const size_t xoff = (size_t)(b0 + bt * 16 + l15) * DMODEL + h * DH;
    xqh[bt][0] = *(const f16x8*)(xi_hi + xoff + lq * 8);
    xql[bt][0] = *(const f16x8*)(xi_lo + xoff + lq * 8);
    const size_t xo1 = xoff + 32 + (lq & 1) * 8;
    f16x8 th = *(const f16x8*)(xi_hi + xo1);
    f16x8 tl = *(const f16x8*)(xi_lo + xo1);
    xqh[bt][1] = (lq < 2) ? th : zf;
    xql[bt][1] = (lq < 2) ? tl : zf;
  }

  float m[2] = {-1e30f, -1e30f}, lsum[2] = {0.f, 0.f};
  f32x4 O[3][2];
#pragma unroll
  for (int mt = 0; mt < 3; mt++)
#pragma unroll
    for (int bt = 0; bt < 2; bt++)
#pragma unroll
      for (int j = 0; j < 4; j++) O[mt][bt][j] = 0.f;

  const int nbase = chunk * FROWS;
  for (int it = 0; it < FROWS / 32; it++) {
    const int gn0 = nbase + it * 32;
    __syncthreads();
    for (int j = tid; j < 384; j += 256) {
      const int tsel = j / 192;
      const int q = j - tsel * 192;
      const int r = q / 6;
      const int d0 = (q - r * 6) * 8;
      const size_t goff = (size_t)(gn0 + r) * DMODEL + h * DH + d0;
      const f16* kp = (tsel ? k_lo : k_hi) + goff;
      f16x8 kv = *(const f16x8*)kp;
      f16x8 vv;
      if (valIsK) {
        vv = kv;
      } else {
        const f16* vp = (tsel ? val_lo : val_hi) + goff;
        vv = *(const f16x8*)vp;
      }
      *(f16x8*)&krow[tsel][r][d0] = kv;
#pragma unroll
      for (int jj = 0; jj < 8; jj++) vT[tsel][d0 + jj][r] = vv[jj];
    }
    __syncthreads();

    f16x8 akh[2][2], akl[2][2];
#pragma unroll
    for (int nt = 0; nt < 2; nt++) {
      const int row = nt * 16 + l15;
      akh[nt][0] = *(const f16x8*)&krow[0][row][lq * 8];
      akl[nt][0] = *(const f16x8*)&krow[1][row][lq * 8];
      f16x8 t0 = *(const f16x8*)&krow[0][row][32 + (lq & 1) * 8];
      f16x8 t1 = *(const f16x8*)&krow[1][row][32 + (lq & 1) * 8];
      akh[nt][1] = (lq < 2) ? t0 : zf;
      akl[nt][1] = (lq < 2) ? t1 : zf;
    }
    f32x4 S[2][2];
#pragma unroll
    for (int nt = 0; nt < 2; nt++)
#pragma unroll
      for (int bt = 0; bt < 2; bt++) {
        f32x4 s = {};
        s = __builtin_amdgcn_mfma_f32_16x16x32_f16(akh[nt][0], xqh[bt][0], s, 0, 0, 0);
        s = __builtin_amdgcn_mfma_f32_16x16x32_f16(akh[nt][1], xqh[bt][1], s, 0, 0, 0);
        s = __builtin_amdgcn_mfma_f32_16x16x32_f16(akh[nt][0], xql[bt][0], s, 0, 0, 0);
        s = __builtin_amdgcn_mfma_f32_16x16x32_f16(akh[nt][1], xql[bt][1], s, 0, 0, 0);
        s = __builtin_amdgcn_mfma_f32_16x16x32_f16(akl[nt][0], xqh[bt][0], s, 0, 0, 0);
        s = __builtin_amdgcn_mfma_f32_16x16x32_f16(akl[nt][1], xqh[bt][1], s, 0, 0, 0);
        S[nt][bt] = s;
      }
    float sc[2];
#pragma unroll
    for (int bt = 0; bt < 2; bt++) {
      float mx = S[0][bt][0];
#pragma unroll
      for (int r = 1; r < 4; r++) mx = fmaxf(mx, S[0][bt][r]);
#pragma unroll
      for (int r = 0; r < 4; r++) mx = fmaxf(mx, S[1][bt][r]);
      mx = fmaxf(mx, __shfl_xor(mx, 16));
      mx = fmaxf(mx, __shfl_xor(mx, 32));
      const float mnew = fmaxf(m[bt], mx);
      sc[bt] = __expf(m[bt] - mnew);
      float ps = 0.f;
#pragma unroll
      for (int nt = 0; nt < 2; nt++) {
        f16x4 ph, pl;
#pragma unroll
        for (int r = 0; r < 4; r++) {
          const float p = __expf(S[nt][bt][r] - mnew);
          ps += p;
          const f16 hh = (f16)p;
          ph[r] = hh;
          pl[r] = (f16)(p - (float)hh);
        }
        *(f16x4*)&pHi[w][bt * 16 + l15][nt * 16 + lq * 4] = ph;
        *(f16x4*)&pLo[w][bt * 16 + l15][nt * 16 + lq * 4] = pl;
      }
      ps += __shfl_xor(ps, 16);
      ps += __shfl_xor(ps, 32);
      lsum[bt] = lsum[bt] * sc[bt] + ps;
      m[bt] = mnew;
    }
    __asm__ volatile("s_waitcnt lgkmcnt(0)" ::: "memory");
    f16x8 avh[3], avl[3];
#pragma unroll
    for (int mt = 0; mt < 3; mt++) {
      avh[mt] = *(const f16x8*)&vT[0][mt * 16 + l15][lq * 8];
      avl[mt] = *(const f16x8*)&vT[1][mt * 16 + l15][lq * 8];
    }
    f16x8 pbh[2], pbl[2];
#pragma unroll
    for (int bt = 0; bt < 2; bt++) {
      pbh[bt] = *(const f16x8*)&pHi[w][bt * 16 + l15][lq * 8];
      pbl[bt] = *(const f16x8*)&pLo[w][bt * 16 + l15][lq * 8];
    }
#pragma unroll
    for (int mt = 0; mt < 3; mt++)
#pragma unroll
      for (int bt = 0; bt < 2; bt++) {
#pragma unroll
        for (int j = 0; j < 4; j++) O[mt][bt][j] *= sc[bt];
        f32x4 o = O[mt][bt];
        o = __builtin_amdgcn_mfma_f32_16x16x32_f16(avh[mt], pbh[bt], o, 0, 0, 0);
        o = __builtin_amdgcn_mfma_f32_16x16x32_f16(avh[mt], pbl[bt], o, 0, 0, 0);
        o = __builtin_amdgcn_mfma_f32_16x16x32_f16(avl[mt], pbh[bt], o, 0, 0, 0);
        O[mt][bt] = o;
      }
  }
  const int pc = h * FCHUNK + chunk;
  if (lq == 0) {
#pragma unroll
    for (int bt = 0; bt < 2; bt++) {
      float* pm = part_ml + ((size_t)pc * BSZ + b0 + bt * 16 + l15) * 2;
      pm[0] = m[bt];
      pm[1] = lsum[bt];
    }
  }
#pragma unroll
  for (int mt = 0; mt < 3; mt++)
#pragma unroll
    for (int bt = 0; bt < 2; bt++) {
      float* po = part_o + ((size_t)pc * BSZ + b0 + bt * 16 + l15) * 48 +
                  mt * 16 + lq * 4;
      *(f32x4*)po = O[mt][bt];
    }
}

// ---------------------------------------------------------------------------
// Combine 64 chunk-partials per (b,h). Grid = B*H blocks of 64 threads.
// ---------------------------------------------------------------------------
__global__ __launch_bounds__(64)
void hopfield_combine(const float* __restrict__ part_ml,
                      const float* __restrict__ part_o, float* __restrict__ dst) {
  const int bh = blockIdx.x;
  const int h = bh >> 7, b = bh & 127;
  const int c = threadIdx.x;
  __shared__ float w[64];
  const float* pm = part_ml + ((size_t)(h * 64 + c) * BSZ + b) * 2;
  const float mp = pm[0];
  const float lp = pm[1];
  float M = mp;
#pragma unroll
  for (int off = 32; off; off >>= 1) M = fmaxf(M, __shfl_xor(M, off));
  const float wp = __expf(mp - M);
  w[c] = wp;
  float L = lp * wp;
#pragma unroll
  for (int off = 32; off; off >>= 1) L += __shfl_xor(L, off);
  __syncthreads();
  if (c < DH) {
    float o = 0.f;
    for (int p = 0; p < 64; p++)
      o += part_o[((size_t)(h * 64 + p) * BSZ + b) * 48 + c] * w[p];
    dst[(size_t)b * DMODEL + h * DH + c] = o / L;
  }
}

// ---------------------------------------------------------------------------
// Top-4 per row with jax tie-breaking (lower index first).
// ---------------------------------------------------------------------------
__global__ __launch_bounds__(256)
void topk_kernel(const float* __restrict__ logits, float* __restrict__ outIdx) {
  const int b = blockIdx.x;
  const int t = threadIdx.x;
  const float* row = logits + (size_t)b * NTOT;
  float v[4] = {-1e30f, -1e30f, -1e30f, -1e30f};
  int id[4] = {0x7fffffff, 0x7fffffff, 0x7fffffff, 0x7fffffff};
  for (int n = t; n < NTOT; n += 256) {
    const float x = row[n];
    if (x > v[3]) {
      v[3] = x; id[3] = n;
#pragma unroll
      for (int s = 3; s > 0; s--) {
        const bool sw = (v[s] > v[s - 1]) || (v[s] == v[s - 1] && id[s] < id[s - 1]);
        if (sw) {
          float tv = v[s]; v[s] = v[s - 1]; v[s - 1] = tv;
          int ti = id[s]; id[s] = id[s - 1]; id[s - 1] = ti;
        }
      }
    }
  }
  __shared__ float sv[256][4];
  __shared__ int si[256][4];
#pragma unroll
  for (int j = 0; j < 4; j++) { sv[t][j] = v[j]; si[t][j] = id[j]; }
  for (int str = 128; str >= 1; str >>= 1) {
    __syncthreads();
    if (t < str) {
      float a[4], c[4];
      int ai[4], ci[4];
#pragma unroll
      for (int j = 0; j < 4; j++) {
        a[j] = sv[t][j]; ai[j] = si[t][j];
        c[j] = sv[t + str][j]; ci[j] = si[t + str][j];
      }
      float rv[4]; int ri[4];
      int p = 0, q = 0;
#pragma unroll
      for (int oo = 0; oo < 4; oo++) {
        const bool ta = (a[p] > c[q]) || (a[p] == c[q] && ai[p] < ci[q]);
        if (ta) { rv[oo] = a[p]; ri[oo] = ai[p]; p++; }
        else    { rv[oo] = c[q]; ri[oo] = ci[q]; q++; }
      }
#pragma unroll
      for (int j = 0; j < 4; j++) { sv[t][j] = rv[j]; si[t][j] = ri[j]; }
    }
  }
  if (t == 0) {
#pragma unroll
    for (int j = 0; j < 4; j++) outIdx[b * 4 + j] = (float)si[0][j];
  }
}

// ---------------------------------------------------------------------------
extern "C" void kernel_launch(void* const* d_in, const int* in_sizes, int n_in,
                              void* d_out, int out_size, void* d_ws, size_t ws_size,
                              hipStream_t stream) {
  const float* qe    = (const float*)d_in[0];
  const float* mb    = (const float*)d_in[1];
  const float* ln_kg = (const float*)d_in[2];
  const float* ln_kb = (const float*)d_in[3];
  const float* ln_qg = (const float*)d_in[4];
  const float* ln_qb = (const float*)d_in[5];
  const float* ln_vg = (const float*)d_in[6];
  const float* ln_vb = (const float*)d_in[7];
  const float* Wq = (const float*)d_in[8];
  const float* bq = (const float*)d_in[9];
  const float* Wk = (const float*)d_in[10];
  const float* bk = (const float*)d_in[11];
  const float* Wv = (const float*)d_in[12];
  const float* bv = (const float*)d_in[13];
  const float* Wo = (const float*)d_in[14];
  const float* bo = (const float*)d_in[15];
  const float* W1 = (const float*)d_in[16];
  const float* b1 = (const float*)d_in[17];
  const float* W2 = (const float*)d_in[18];
  const float* b2 = (const float*)d_in[19];

  float* out = (float*)d_out;  // [0..511] indices (as float), then logits
  float* logits = out + BSZ * 4;

  const size_t ND16 = (size_t)NTOT * DMODEL / 2;  // fp16 N*D buffer in floats
  const size_t PART = (size_t)NHEAD * FCHUNK * BSZ * (2 + 48);
  // Fast path needs the nh hi/lo region (2*ND16); fallback only PART.
  const size_t fixed = 3 * NTOT + 768 + 4 * ND16 + 4 * (size_t)BSZ * DMODEL +
                       4 * (size_t)BSZ * DMODEL / 2 +
                       2 * (size_t)2 * DMODEL * DMODEL / 2 + 2 * DMODEL;
  const bool fast = (fixed + 2 * ND16) * sizeof(float) <= ws_size;
  const size_t nhpart = fast ? 2 * ND16 : PART;

  float* ws = (float*)d_ws;
  size_t off = 0;
  auto alloc = [&](size_t n) { float* p = ws + off; off += n; return p; };
  float* mb_mean = alloc(NTOT);
  float* mb_rstd = alloc(NTOT);
  float* mb_l2i  = alloc(NTOT);
  float* q_mean  = alloc(128);
  float* q_rstd  = alloc(128);
  float* rq_inv  = alloc(128);
  float* pad_    = alloc(384);
  f16* k_hi = (f16*)alloc(ND16);  // [N][768] fp16 (mb16_hi overlays later)
  f16* k_lo = (f16*)alloc(ND16);  // (mb16_lo overlays later)
  f16* v_hi = (f16*)alloc(ND16);
  f16* v_lo = (f16*)alloc(ND16);
  float* nhpart_base = alloc(nhpart);  // nh hi/lo (pre-proj) OR partials
  f16* nh_hi = (f16*)nhpart_base;
  f16* nh_lo = (f16*)(nhpart_base + ND16);
  float* part_ml = nhpart_base;
  float* part_o  = nhpart_base + (size_t)NHEAD * FCHUNK * BSZ * 2;
  float* xi   = alloc((size_t)BSZ * DMODEL);
  float* conv = alloc((size_t)BSZ * DMODEL);
  float* comb = alloc((size_t)BSZ * DMODEL);
  float* h1   = alloc((size_t)BSZ * DMODEL);
  f16* xi_hi = (f16*)alloc((size_t)BSZ * DMODEL / 2);
  f16* xi_lo = (f16*)alloc((size_t)BSZ * DMODEL / 2);
  f16* rq_hi = (f16*)alloc((size_t)BSZ * DMODEL / 2);
  f16* rq_lo = (f16*)alloc((size_t)BSZ * DMODEL / 2);
  f16* Wc_hi = (f16*)alloc((size_t)2 * DMODEL * DMODEL / 2);
  f16* Wc_lo = (f16*)alloc((size_t)2 * DMODEL * DMODEL / 2);
  float* biasc = alloc(2 * DMODEL);
  f16* mb16_hi = (f16*)k_hi;  // overlay: valid only after last flash round
  f16* mb16_lo = (f16*)k_lo;
  (void)in_sizes; (void)n_in; (void)out_size; (void)pad_;

  // 1. stats + W prep
  row_stats<<<NTOT / 4, 256, 0, stream>>>(mb, NTOT, mb_mean, mb_rstd, mb_l2i);
  row_stats<<<BSZ / 4, 256, 0, stream>>>(qe, BSZ, q_mean, q_rstd, nullptr);
  prep_w<<<2 * DMODEL / 4, 256, 0, stream>>>(Wk, bk, ln_kg, ln_kb,
                                             Wv, bv, ln_vg, ln_vb,
                                             Wc_hi, Wc_lo, biasc);

  // 2. projections: k/v via MFMA (pre-split A when workspace allows); q fp32
  if (fast) {
    split_ln<<<(NTOT * DMODEL / 8) / 256, 256, 0, stream>>>(
        mb, mb_mean, mb_rstd, nh_hi, nh_lo);
    proj_dual_v2<<<dim3(2 * DMODEL / 128, NTOT / 128), 256, 0, stream>>>(
        nh_hi, nh_lo, Wc_hi, Wc_lo, biasc, k_hi, k_lo, v_hi, v_lo);
  } else {
    proj_dual_insplit<<<dim3(2 * DMODEL / 128, NTOT / 128), 256, 0, stream>>>(
        mb, mb_mean, mb_rstd, Wc_hi, Wc_lo, biasc, k_hi, k_lo, v_hi, v_lo);
  }
  ln_gemm_f32<<<dim3(DMODEL / 64, BSZ / 64), 256, 0, stream>>>(
      qe, q_mean, q_rstd, ln_qg, ln_qb, Wq, bq, xi);

  // 3. Hopfield: 5 updates (value = k), then readout (value = v)
  for (int r = 0; r < 6; r++) {
    const int valIsK = (r != 5);
    const f16* valHi = valIsK ? k_hi : v_hi;
    const f16* valLo = valIsK ? k_lo : v_lo;
    float* dst = (r == 5) ? conv : xi;
    split_xi_k<<<96, 256, 0, stream>>>(xi, xi_hi, xi_lo);
    flash_round<<<dim3(FCHUNK, NHEAD), 256, 0, stream>>>(
        k_hi, k_lo, valHi, valLo, xi_hi, xi_lo, part_ml, part_o, valIsK);
    hopfield_combine<<<BSZ * NHEAD, 64, 0, stream>>>(part_ml, part_o, dst);
  }

  // 4. readout MLP
  gemm_bias<<<dim3(DMODEL / 64, BSZ / 64), 256, 0, stream>>>(conv, Wo, bo, qe, comb, 0);
  gemm_bias<<<dim3(DMODEL / 64, BSZ / 64), 256, 0, stream>>>(comb, W1, b1, nullptr, h1, 1);
  float* rq = conv;  // conv dead; reuse for rq
  gemm_bias<<<dim3(DMODEL / 64, BSZ / 64), 256, 0, stream>>>(h1, W2, b2, nullptr, rq, 0);

  // 5. cosine logits via MFMA (mb split overlays dead k region)
  row_stats<<<BSZ / 4, 256, 0, stream>>>(rq, BSZ, q_mean, q_rstd, rq_inv);
  split_plain<<<(NTOT * DMODEL / 8) / 256, 256, 0, stream>>>(mb, mb16_hi, mb16_lo);
  split_plain<<<(BSZ * DMODEL / 8) / 256, 256, 0, stream>>>(rq, rq_hi, rq_lo);
  logits_mfma<<<NTOT / 128, 256, 0, stream>>>(mb16_hi, mb16_lo, rq_hi, rq_lo,
                                              rq_inv, mb_l2i, logits);

  // 6. top-4 indices
  topk_kernel<<<BSZ, 256, 0, stream>>>(logits, out);
}